// Round 8
// baseline (247.121 us; speedup 1.0000x reference)
//
#include <hip/hip_runtime.h>

// KinematicWaveRouting: outlet(t) = basin_area*50 * sum_k w[k]*runoff(t-k),
// w[k] = P(Binom(k,0.9) <= 19): exactly 1.0 for k<=19 (box part, slid),
// fast decay after; K=32 taps.
//
// R9 -> R10 (R8 structure + three attributable fixes):
//  (a) padded LDS addressing pidx(q)=q+(q>>3) instead of XOR swizzle.
//      The stride-2 b128 read (quads 2*tid+c) is provably 2-way conflicted
//      under ANY xor-of-high-bits swizzle (parity argument); padding spreads
//      both the consecutive write and the stride-2 read to multiplicity 2
//      per 16-lane phase = free. Predict SQ_LDS_BANK_CONFLICT 8e6 -> ~0.
//  (b) non-temporal output stores: output is never re-read, but its L3
//      allocations were evicting the (fill-dirtied, L3-resident) input --
//      FETCH_SIZE was 66MB ~= half the input. NT stores preserve input
//      residency. Predict FETCH_SIZE 66 -> 35-50MB.
//  (c) double-buffer pipeline kept, with sched_barrier(0) pinning next-tile
//      load ISSUE above compute (hipcc otherwise sinks the loads to the
//      ds_write -- the R7 lesson); NBLK 2048 -> 8 tiles/block.

#define KTAPS 32
#define RPT   8                      // outputs per thread along t
#define TPB   256
#define TILE_T (TPB * RPT)           // 2048 t-values per tile
#define NQ   ((TILE_T + KTAPS) / 4)  // 520 staged quads (16B) incl. 32-halo
#define NQP  (NQ + NQ / 8 + 1)       // 586 padded slots
#define NBLK 2048                    // grid; 8 tiles per block

struct WTab { float w[KTAPS]; };

typedef float vf4 __attribute__((ext_vector_type(4)));

__device__ __forceinline__ int pidx(int q) { return q + (q >> 3); }

__global__ __launch_bounds__(TPB) void kwr_fir_lds_kernel(
    const float* __restrict__ runoff,
    const float* __restrict__ basin_area,
    float* __restrict__ out,
    int T, int tiles_per_row, int n_tiles, WTab wt)
{
    __shared__ float4 lds[2][NQP];
    const int tid = threadIdx.x;

    float4 st[3];
    int cur = 0;
    int ti = blockIdx.x;

    // ---- prologue: load + stage first tile into buf0 ----------------------
    {
        const int b      = ti / tiles_per_row;
        const int tile   = ti - b * tiles_per_row;
        const int tstart = tile * TILE_T - KTAPS;          // row-local
        const float4* gsrc = (const float4*)(runoff + (long long)b * T + tstart);
        #pragma unroll
        for (int p = 0; p < 3; ++p) {
            int q = tid + p * TPB;
            if (q < NQ)
                st[p] = (tstart + 4 * q >= 0) ? gsrc[q]
                                              : make_float4(0.f, 0.f, 0.f, 0.f);
        }
        #pragma unroll
        for (int p = 0; p < 3; ++p) {
            int q = tid + p * TPB;
            if (q < NQ) lds[0][pidx(q)] = st[p];
        }
    }

    for (; ti < n_tiles; ti += NBLK) {
        const int nx = ti + NBLK;
        __syncthreads();                       // buf[cur] visible to all

        // ---- issue next tile's global loads EARLY -------------------------
        if (nx < n_tiles) {
            const int nb      = nx / tiles_per_row;
            const int ntile   = nx - nb * tiles_per_row;
            const int ntstart = ntile * TILE_T - KTAPS;
            const float4* gsrc =
                (const float4*)(runoff + (long long)nb * T + ntstart);
            #pragma unroll
            for (int p = 0; p < 3; ++p) {
                int q = tid + p * TPB;
                if (q < NQ)
                    st[p] = (ntstart + 4 * q >= 0)
                                ? gsrc[q] : make_float4(0.f, 0.f, 0.f, 0.f);
            }
        }
        // pin the loads above the compute phase; waits stay at the ds_write
        __builtin_amdgcn_sched_barrier(0);

        // ---- compute current tile from buf[cur] ---------------------------
        {
            const int b    = ti / tiles_per_row;
            const int tile = ti - b * tiles_per_row;

            float buf[RPT + KTAPS];
            #pragma unroll
            for (int c = 0; c < (RPT + KTAPS) / 4; ++c) {
                float4 v = lds[cur][pidx(2 * tid + c)];
                buf[4*c+0] = v.x; buf[4*c+1] = v.y;
                buf[4*c+2] = v.z; buf[4*c+3] = v.w;
            }

            // taps 0..19 == 1.0 exactly: box sum slid across the 8 outputs
            float acc[RPT];
            {
                float S = 0.0f;
                #pragma unroll
                for (int m = 13; m <= 32; ++m) S += buf[m];
                acc[0] = S;
                #pragma unroll
                for (int r = 1; r < RPT; ++r) {
                    S += buf[r + 32] - buf[r + 12];
                    acc[r] = S;
                }
            }
            #pragma unroll
            for (int k = 20; k < KTAPS; ++k) {
                const float wk = wt.w[k];
                #pragma unroll
                for (int r = 0; r < RPT; ++r)
                    acc[r] = fmaf(wk, buf[32 + r - k], acc[r]);
            }

            const float s = basin_area[b] * 50.0f;   // (1e6/1000/3600/20)*DT
            float* orow = out + (long long)b * T + tile * TILE_T + tid * RPT;
            vf4 o0 = {acc[0]*s, acc[1]*s, acc[2]*s, acc[3]*s};
            vf4 o1 = {acc[4]*s, acc[5]*s, acc[6]*s, acc[7]*s};
            __builtin_nontemporal_store(o0, (vf4*)orow);
            __builtin_nontemporal_store(o1, (vf4*)orow + 1);
        }

        // ---- write the in-flight regs into the other buffer ---------------
        if (nx < n_tiles) {
            #pragma unroll
            for (int p = 0; p < 3; ++p) {
                int q = tid + p * TPB;
                if (q < NQ) lds[cur ^ 1][pidx(q)] = st[p];
            }
        }
        cur ^= 1;
    }
}

extern "C" void kernel_launch(void* const* d_in, const int* in_sizes, int n_in,
                              void* d_out, int out_size, void* d_ws, size_t ws_size,
                              hipStream_t stream)
{
    const float* runoff     = (const float*)d_in[0];
    const float* basin_area = (const float*)d_in[1];
    float* out = (float*)d_out;

    const int B = in_sizes[1];            // basin_area has B elements
    const int T = in_sizes[0] / B;        // runoff is (B, T)

    // Impulse response of the linear recurrence, computed in double.
    WTab wt;
    double Q[21];
    for (int j = 0; j <= 20; ++j) Q[j] = (j >= 1) ? 1.0 : 0.0;
    wt.w[0] = 1.0f;
    for (int k = 1; k < KTAPS; ++k) {
        for (int j = 20; j >= 1; --j) Q[j] = 0.1 * Q[j] + 0.9 * Q[j - 1];
        wt.w[k] = (float)Q[20];
    }

    const int tiles_per_row = T / TILE_T;           // 4096 / 2048 = 2
    const int n_tiles = B * tiles_per_row;          // 16384
    const int nblk = (n_tiles < NBLK) ? n_tiles : NBLK;

    kwr_fir_lds_kernel<<<nblk, TPB, 0, stream>>>(runoff, basin_area, out,
                                                 T, tiles_per_row, n_tiles, wt);
}